// Round 9
// baseline (582.111 us; speedup 1.0000x reference)
//
#include <hip/hip_runtime.h>
#include <hip/hip_bf16.h>

#define NN 50000
#define EE 600000
#define DD 128
#define RR 7
#define SS 8            // R + self-loop slot
#define KK 1024         // SS*DD
#define GG 32
#define BMF 16          // rows per fused block
#define NSEG (NN * RR)  // 350000 CSR segments
#define NB1 ((NSEG + 1023) / 1024)   // 342 scan blocks

typedef float f32x4 __attribute__((ext_vector_type(4)));
typedef short short8 __attribute__((ext_vector_type(8)));
typedef unsigned short u16x8 __attribute__((ext_vector_type(8)));

static __device__ __forceinline__ unsigned short f2bf(float f) {
    union { float f; unsigned u; } v; v.f = f;
    unsigned r = v.u + 0x7fff + ((v.u >> 16) & 1);
    return (unsigned short)(r >> 16);
}
static __device__ __forceinline__ float bf2f(unsigned short u) {
    union { unsigned u; float f; } v; v.u = ((unsigned)u) << 16;
    return v.f;
}

// ---------------- weights prep: W^T bf16 [j][k], bias = lin_b + sl_b ----------------
__global__ void prep_w(const float* __restrict__ lin_w, const float* __restrict__ sl_w,
                       const float* __restrict__ lin_b, const float* __restrict__ sl_b,
                       unsigned short* __restrict__ Wt, float* __restrict__ bias) {
    int idx = blockIdx.x * 256 + threadIdx.x;
    if (idx < DD) bias[idx] = lin_b[idx] + sl_b[idx];
    if (idx >= DD * KK) return;
    int j  = idx >> 10;
    int kk = idx & 1023;
    float w = (kk < RR * DD) ? lin_w[kk * DD + j] : sl_w[(kk - RR * DD) * DD + j];
    Wt[(size_t)j * KK + kk] = f2bf(w);
}

// ---------------- CSR build ----------------
__global__ void zero_ints(int* __restrict__ p, int n) {
    int i = blockIdx.x * 256 + threadIdx.x;
    if (i < n) p[i] = 0;
}

__global__ void hist(const int* __restrict__ node_out, const int* __restrict__ rel,
                     int* __restrict__ counts) {
    int e = blockIdx.x * 256 + threadIdx.x;
    if (e >= EE) return;
    atomicAdd(&counts[node_out[e] * RR + rel[e]], 1);
}

__global__ __launch_bounds__(256) void scan1(const int* __restrict__ counts,
                                             int* __restrict__ start, int* __restrict__ bsum) {
    __shared__ int s[256];
    int tid = threadIdx.x;
    int base = blockIdx.x * 1024 + tid * 4;
    int v[4], sum = 0;
    #pragma unroll
    for (int j = 0; j < 4; ++j) {
        v[j] = (base + j < NSEG) ? counts[base + j] : 0;
        sum += v[j];
    }
    s[tid] = sum; __syncthreads();
    for (int off = 1; off < 256; off <<= 1) {
        int t = (tid >= off) ? s[tid - off] : 0;
        __syncthreads();
        s[tid] += t;
        __syncthreads();
    }
    int run = s[tid] - sum;
    if (tid == 255) bsum[blockIdx.x] = s[255];
    #pragma unroll
    for (int j = 0; j < 4; ++j) {
        if (base + j < NSEG) { start[base + j] = run; run += v[j]; }
    }
}

__global__ __launch_bounds__(512) void scan2(int* __restrict__ bsum) {
    __shared__ int s[512];
    int tid = threadIdx.x;
    int v = (tid < NB1) ? bsum[tid] : 0;
    s[tid] = v; __syncthreads();
    for (int off = 1; off < 512; off <<= 1) {
        int t = (tid >= off) ? s[tid - off] : 0;
        __syncthreads();
        s[tid] += t;
        __syncthreads();
    }
    if (tid < NB1) bsum[tid] = s[tid] - v;
}

// segd[i] = {global start, count}
__global__ void scan3(const int* __restrict__ start, const int* __restrict__ bsum,
                      const int* __restrict__ counts, int2* __restrict__ segd) {
    int i = blockIdx.x * 256 + threadIdx.x;
    if (i < NSEG) segd[i] = make_int2(start[i] + bsum[i >> 10], counts[i]);
}

__global__ void fill(const int* __restrict__ node_in, const int* __restrict__ node_out,
                     const int* __restrict__ rel, const float* __restrict__ ew,
                     const int2* __restrict__ segd, int* __restrict__ cursor,
                     int2* __restrict__ edges) {
    int e = blockIdx.x * 256 + threadIdx.x;
    if (e >= EE) return;
    int seg = node_out[e] * RR + rel[e];
    int pos = segd[seg].x + atomicAdd(&cursor[seg], 1);
    edges[pos] = make_int2(node_in[e], __float_as_int(ew[e]));
}

// layer-0 bf16 shadow of x.  EXACTLY NN*32 threads (6250 blocks).
__global__ void init_hb(const float* __restrict__ x, unsigned short* __restrict__ hb) {
    int t = blockIdx.x * 256 + threadIdx.x;     // [0, NN*32)
    if (t >= NN * 32) return;
    f32x4 v = ((const f32x4*)x)[t];
    unsigned long long pack = (unsigned long long)f2bf(v.x)
                            | ((unsigned long long)f2bf(v.y) << 16)
                            | ((unsigned long long)f2bf(v.z) << 32)
                            | ((unsigned long long)f2bf(v.w) << 48);
    ((unsigned long long*)hb)[t] = pack;
}

// ---------------- fused layer v2: 16 rows/block, zipped 7-slot gather + MFMA ----------------
// 256 threads = 16 row-groups x 16 lanes (gather) = 4 waves (mfma: wave w -> cols 32w..32w+32).
// LDS: sA [16 rows][128 chunks of 16B], XOR-swizzled chunk index; sSeg 112 int2.
__global__ __launch_bounds__(256) void fused16(
        const unsigned short* __restrict__ hb,       // bf16 h  [N][128]
        const int2* __restrict__ segd,
        const int2* __restrict__ edges,
        const unsigned short* __restrict__ Wt,       // [128 j][1024 k]
        const float* __restrict__ bias,
        const float* __restrict__ hprev,             // fp32 h  [N][128]
        float* __restrict__ hout,
        unsigned short* __restrict__ hb_next,
        int write_next) {
    __shared__ u16x8 sA[BMF * 128];                  // 32 KB
    __shared__ int2 sSeg[BMF * RR];                  // 896 B
    int tid = threadIdx.x;
    int bm0 = blockIdx.x * BMF;

    if (tid < BMF * RR) sSeg[tid] = segd[bm0 * RR + tid];

    int row = tid >> 4;            // 0..15
    int c   = tid & 15;            // 16B chunk within row
    int node = bm0 + row;
    int sw  = row & 7;
    __syncthreads();

    // ---- zipped gather: 7 independent chains per iteration ----
    int cs[7], cn[7];
    int mx = 0;
    #pragma unroll
    for (int s = 0; s < 7; ++s) {
        int2 sd = sSeg[row * RR + s];
        cs[s] = sd.x; cn[s] = sd.y;
        mx = (sd.y > mx) ? sd.y : mx;
    }
    u16x8 hself = ((const u16x8*)hb)[(size_t)node * 16 + c];
    float acc[7][8] = {};
    for (int i = 0; i < mx; ++i) {
        #pragma unroll
        for (int s = 0; s < 7; ++s) {
            if (i < cn[s]) {
                int2 e = edges[cs[s] + i];
                float w = __int_as_float(e.y);
                u16x8 hv = ((const u16x8*)hb)[(size_t)e.x * 16 + c];
                #pragma unroll
                for (int j = 0; j < 8; ++j) acc[s][j] += bf2f(hv[j]) * w;
            }
        }
    }
    #pragma unroll
    for (int s = 0; s < 7; ++s) {
        u16x8 o;
        #pragma unroll
        for (int j = 0; j < 8; ++j) o[j] = f2bf(acc[s][j]);
        sA[row * 128 + ((s * 16 + c) ^ sw)] = o;
    }
    sA[row * 128 + ((112 + c) ^ sw)] = hself;        // self-loop slot (already bf16)
    __syncthreads();

    // ---- MFMA: rows 0..15, wave w covers cols [32w, 32w+32) ----
    int wid = tid >> 6, lane = tid & 63;
    int lm = lane & 15, lg = lane >> 4;
    int j0 = wid * 32;
    // prefetch epilogue operands
    float bs[2], hp[2][4];
    #pragma unroll
    for (int ni = 0; ni < 2; ++ni) {
        bs[ni] = bias[j0 + ni * 16 + lm];
        #pragma unroll
        for (int v = 0; v < 4; ++v)
            hp[ni][v] = hprev[(size_t)(bm0 + lg * 4 + v) * DD + j0 + ni * 16 + lm];
    }
    f32x4 acc2[2] = {};
    int swm = lm & 7;
    for (int t = 0; t < 32; ++t) {
        short8 af = ((const short8*)sA)[lm * 128 + ((t * 4 + lg) ^ swm)];
        short8 b0 = *(const short8*)(Wt + (size_t)(j0 + lm) * KK + t * 32 + lg * 8);
        short8 b1 = *(const short8*)(Wt + (size_t)(j0 + 16 + lm) * KK + t * 32 + lg * 8);
        acc2[0] = __builtin_amdgcn_mfma_f32_16x16x32_bf16(af, b0, acc2[0], 0, 0, 0);
        acc2[1] = __builtin_amdgcn_mfma_f32_16x16x32_bf16(af, b1, acc2[1], 0, 0, 0);
    }
    // ---- epilogue: D row = lg*4+v (block-local), col = j0 + ni*16 + lm ----
    #pragma unroll
    for (int ni = 0; ni < 2; ++ni) {
        #pragma unroll
        for (int v = 0; v < 4; ++v) {
            int gm = bm0 + lg * 4 + v;               // 3125*16 = 50000 exact, no guard
            int col = j0 + ni * 16 + lm;
            float val = fmaxf(acc2[ni][v] + bs[ni], 0.f) + hp[ni][v];
            hout[(size_t)gm * DD + col] = val;
            if (write_next) hb_next[(size_t)gm * DD + col] = f2bf(val);
        }
    }
}

__global__ void zero_gf(float* gf) {
    int t = blockIdx.x * 256 + threadIdx.x;
    if (t < GG * DD) gf[t] = 0.f;
}

// Parallel readout: block = 128 nodes, 8 row-streams x 32 lanes (f32x4 cols).
__global__ __launch_bounds__(256) void readout(const float* __restrict__ h,
                                               const int* __restrict__ n2g,
                                               float* __restrict__ gf) {
    int c0 = blockIdx.x * 128;
    int rg = threadIdx.x >> 5, d4 = threadIdx.x & 31;
    f32x4 acc = {0.f, 0.f, 0.f, 0.f};
    int cur = -1;
    #pragma unroll 4
    for (int it = 0; it < 16; ++it) {
        int row = c0 + it * 8 + rg;
        if (row >= NN) break;
        int g = n2g[row];
        if (g != cur) {
            if (cur >= 0) {
                atomicAdd(&gf[cur * DD + d4 * 4 + 0], acc.x);
                atomicAdd(&gf[cur * DD + d4 * 4 + 1], acc.y);
                atomicAdd(&gf[cur * DD + d4 * 4 + 2], acc.z);
                atomicAdd(&gf[cur * DD + d4 * 4 + 3], acc.w);
            }
            cur = g;
            acc = (f32x4){0.f, 0.f, 0.f, 0.f};
        }
        acc += ((const f32x4*)h)[(size_t)row * 32 + d4];
    }
    if (cur >= 0) {
        atomicAdd(&gf[cur * DD + d4 * 4 + 0], acc.x);
        atomicAdd(&gf[cur * DD + d4 * 4 + 1], acc.y);
        atomicAdd(&gf[cur * DD + d4 * 4 + 2], acc.z);
        atomicAdd(&gf[cur * DD + d4 * 4 + 3], acc.w);
    }
}

extern "C" void kernel_launch(void* const* d_in, const int* in_sizes, int n_in,
                              void* d_out, int out_size, void* d_ws, size_t ws_size,
                              hipStream_t stream) {
    const float* x      = (const float*)d_in[0];
    const int* node_in  = (const int*)d_in[1];
    const int* node_out = (const int*)d_in[2];
    const int* relation = (const int*)d_in[3];
    const float* ew     = (const float*)d_in[4];
    const int* n2g      = (const int*)d_in[5];
    const float* sl_w[3]  = {(const float*)d_in[8],  (const float*)d_in[12], (const float*)d_in[16]};
    const float* sl_b[3]  = {(const float*)d_in[9],  (const float*)d_in[13], (const float*)d_in[17]};
    const float* lin_w[3] = {(const float*)d_in[10], (const float*)d_in[14], (const float*)d_in[18]};
    const float* lin_b[3] = {(const float*)d_in[11], (const float*)d_in[15], (const float*)d_in[19]};

    float* out = (float*)d_out;
    float* gf = out;                       // [G,D]
    float* nf = out + GG * DD;             // [N,D] node_feature (doubles as h buffer)

    char* ws = (char*)d_ws;
    size_t off = 0;
    unsigned short* hb0 = (unsigned short*)(ws + off); off += (size_t)NN * DD * 2;    // 12.8 MB
    unsigned short* hb1 = (unsigned short*)(ws + off); off += (size_t)NN * DD * 2;    // 12.8 MB
    float* hA   = (float*)(ws + off);            off += (size_t)NN * DD * 4;          // 25.6 MB
    unsigned short* Wt = (unsigned short*)(ws + off); off += (size_t)3 * KK * DD * 2;
    float* bias = (float*)(ws + off);            off += 3 * DD * 4;
    int* counts = (int*)(ws + off);              off += (size_t)NSEG * 4;
    int* cursor = (int*)(ws + off);              off += (size_t)NSEG * 4;
    int* start  = (int*)(ws + off);              off += (size_t)NSEG * 4;
    int2* segd  = (int2*)(ws + off);             off += (size_t)NSEG * 8;
    int* bsum   = (int*)(ws + off);              off += 512 * 4;
    int2* edges = (int2*)(ws + off);             off += (size_t)EE * 8;

    for (int l = 0; l < 3; ++l)
        prep_w<<<512, 256, 0, stream>>>(lin_w[l], sl_w[l], lin_b[l], sl_b[l],
                                        Wt + (size_t)l * KK * DD, bias + l * DD);

    // CSR build (edge topology is layer-invariant)
    zero_ints<<<(2 * NSEG + 255) / 256, 256, 0, stream>>>(counts, 2 * NSEG);
    hist<<<(EE + 255) / 256, 256, 0, stream>>>(node_out, relation, counts);
    scan1<<<NB1, 256, 0, stream>>>(counts, start, bsum);
    scan2<<<1, 512, 0, stream>>>(bsum);
    scan3<<<(NSEG + 255) / 256, 256, 0, stream>>>(start, bsum, counts, segd);
    fill<<<(EE + 255) / 256, 256, 0, stream>>>(node_in, node_out, relation, ew,
                                               segd, cursor, edges);
    init_hb<<<(NN * 32) / 256, 256, 0, stream>>>(x, hb0);   // 6250 blocks exact

    const float* hcur = x;
    float* houts[3] = { nf, hA, nf };
    unsigned short* hbs[2] = { hb0, hb1 };
    for (int l = 0; l < 3; ++l) {
        fused16<<<NN / BMF, 256, 0, stream>>>(
            hbs[l & 1], segd, edges, Wt + (size_t)l * KK * DD, bias + l * DD,
            hcur, houts[l], hbs[(l + 1) & 1], l < 2 ? 1 : 0);
        hcur = houts[l];
    }
    zero_gf<<<(GG * DD + 255) / 256, 256, 0, stream>>>(gf);
    readout<<<(NN + 127) / 128, 256, 0, stream>>>(nf, n2g, gf);
}

// Round 10
// 548.666 us; speedup vs baseline: 1.0610x; 1.0610x over previous
//
#include <hip/hip_runtime.h>
#include <hip/hip_bf16.h>

#define NN 50000
#define EE 600000
#define DD 128
#define RR 7
#define SS 8            // R + self-loop slot
#define KK 1024         // SS*DD
#define GG 32
#define NSEG (NN * RR)  // 350000 CSR segments
#define NB1 ((NSEG + 1023) / 1024)   // 342 scan blocks

typedef float f32x4 __attribute__((ext_vector_type(4)));
typedef float f32x2 __attribute__((ext_vector_type(2)));
typedef short short8 __attribute__((ext_vector_type(8)));

static __device__ __forceinline__ unsigned short f2bf(float f) {
    union { float f; unsigned u; } v; v.f = f;
    unsigned r = v.u + 0x7fff + ((v.u >> 16) & 1);
    return (unsigned short)(r >> 16);
}
static __device__ __forceinline__ float bf2f(unsigned short u) {
    union { unsigned u; float f; } v; v.u = ((unsigned)u) << 16;
    return v.f;
}

// ---------------- weights prep: W^T bf16 [j][k], bias = lin_b + sl_b ----------------
__global__ void prep_w(const float* __restrict__ lin_w, const float* __restrict__ sl_w,
                       const float* __restrict__ lin_b, const float* __restrict__ sl_b,
                       unsigned short* __restrict__ Wt, float* __restrict__ bias) {
    int idx = blockIdx.x * 256 + threadIdx.x;
    if (idx < DD) bias[idx] = lin_b[idx] + sl_b[idx];
    if (idx >= DD * KK) return;
    int j  = idx >> 10;
    int kk = idx & 1023;
    float w = (kk < RR * DD) ? lin_w[kk * DD + j] : sl_w[(kk - RR * DD) * DD + j];
    Wt[(size_t)j * KK + kk] = f2bf(w);
}

// ---------------- CSR build ----------------
__global__ void zero_ints(int* __restrict__ p, int n) {
    int i = blockIdx.x * 256 + threadIdx.x;
    if (i < n) p[i] = 0;
}

__global__ void hist(const int* __restrict__ node_out, const int* __restrict__ rel,
                     int* __restrict__ counts) {
    int e = blockIdx.x * 256 + threadIdx.x;
    if (e >= EE) return;
    atomicAdd(&counts[node_out[e] * RR + rel[e]], 1);
}

__global__ __launch_bounds__(256) void scan1(const int* __restrict__ counts,
                                             int* __restrict__ start, int* __restrict__ bsum) {
    __shared__ int s[256];
    int tid = threadIdx.x;
    int base = blockIdx.x * 1024 + tid * 4;
    int v[4], sum = 0;
    #pragma unroll
    for (int j = 0; j < 4; ++j) {
        v[j] = (base + j < NSEG) ? counts[base + j] : 0;
        sum += v[j];
    }
    s[tid] = sum; __syncthreads();
    for (int off = 1; off < 256; off <<= 1) {
        int t = (tid >= off) ? s[tid - off] : 0;
        __syncthreads();
        s[tid] += t;
        __syncthreads();
    }
    int run = s[tid] - sum;
    if (tid == 255) bsum[blockIdx.x] = s[255];
    #pragma unroll
    for (int j = 0; j < 4; ++j) {
        if (base + j < NSEG) { start[base + j] = run; run += v[j]; }
    }
}

__global__ __launch_bounds__(512) void scan2(int* __restrict__ bsum) {
    __shared__ int s[512];
    int tid = threadIdx.x;
    int v = (tid < NB1) ? bsum[tid] : 0;
    s[tid] = v; __syncthreads();
    for (int off = 1; off < 512; off <<= 1) {
        int t = (tid >= off) ? s[tid - off] : 0;
        __syncthreads();
        s[tid] += t;
        __syncthreads();
    }
    if (tid < NB1) bsum[tid] = s[tid] - v;
}

// segd[i] = {global start, count}
__global__ void scan3(const int* __restrict__ start, const int* __restrict__ bsum,
                      const int* __restrict__ counts, int2* __restrict__ segd) {
    int i = blockIdx.x * 256 + threadIdx.x;
    if (i < NSEG) segd[i] = make_int2(start[i] + bsum[i >> 10], counts[i]);
}

// record: x = (rel << 16) | node_in  (node_in < 50000 < 2^16), y = weight bits
__global__ void fill(const int* __restrict__ node_in, const int* __restrict__ node_out,
                     const int* __restrict__ rel, const float* __restrict__ ew,
                     const int2* __restrict__ segd, int* __restrict__ cursor,
                     int2* __restrict__ edges) {
    int e = blockIdx.x * 256 + threadIdx.x;
    if (e >= EE) return;
    int seg = node_out[e] * RR + rel[e];
    int pos = segd[seg].x + atomicAdd(&cursor[seg], 1);
    edges[pos] = make_int2((rel[e] << 16) | node_in[e], __float_as_int(ew[e]));
}

// layer-0 bf16 shadow of x.  EXACTLY NN*32 threads (6250 blocks).
__global__ void init_hb(const float* __restrict__ x, unsigned short* __restrict__ hb) {
    int t = blockIdx.x * 256 + threadIdx.x;     // [0, NN*32)
    if (t >= NN * 32) return;
    f32x4 v = ((const f32x4*)x)[t];
    unsigned long long pack = (unsigned long long)f2bf(v.x)
                            | ((unsigned long long)f2bf(v.y) << 16)
                            | ((unsigned long long)f2bf(v.z) << 32)
                            | ((unsigned long long)f2bf(v.w) << 48);
    ((unsigned long long*)hb)[t] = pack;
}

// ---------------- fused v3: wave-per-node linear edge walk + MFMA ----------------
// 512 threads = 8 waves; block = 16 nodes (wave w gathers nodes 2w, 2w+1).
// LDS sA: [16 rows][1024 bf16], 16B chunks XOR-swizzled by (row&7).
#define GATHER_NODE(half)                                                          \
    {                                                                              \
        int row = wv * 2 + (half);                                                 \
        int node = bm0 + row;                                                      \
        int st  = segd[node * RR].x;                                               \
        int2 s6 = segd[node * RR + 6];                                             \
        int end = s6.x + s6.y;                                                     \
        f32x2 a0={0,0},a1={0,0},a2={0,0},a3={0,0},a4={0,0},a5={0,0},a6={0,0};      \
        int2 r0 = edges[st];                                                       \
        int2 r1 = edges[st + 1];                                                   \
        unsigned hv0 = *(const unsigned*)(hb + (size_t)(r0.x & 0xFFFF) * DD + lane * 2); \
        for (int i = st; i < end; ++i) {                                           \
            int2 rn = edges[i + 2];                                                \
            unsigned hvn = *(const unsigned*)(hb + (size_t)(r1.x & 0xFFFF) * DD + lane * 2); \
            float w = __int_as_float(r0.y);                                        \
            float lo = bf2f((unsigned short)(hv0 & 0xFFFF)) * w;                   \
            float hi = bf2f((unsigned short)(hv0 >> 16)) * w;                      \
            switch (r0.x >> 16) {                                                  \
                case 0: a0.x += lo; a0.y += hi; break;                             \
                case 1: a1.x += lo; a1.y += hi; break;                             \
                case 2: a2.x += lo; a2.y += hi; break;                             \
                case 3: a3.x += lo; a3.y += hi; break;                             \
                case 4: a4.x += lo; a4.y += hi; break;                             \
                case 5: a5.x += lo; a5.y += hi; break;                             \
                default: a6.x += lo; a6.y += hi; break;                            \
            }                                                                      \
            r0 = r1; r1 = rn; hv0 = hvn;                                           \
        }                                                                          \
        int sw = row & 7;                                                          \
        char* rowp = (char*)sA + row * 2048;                                       \
        int cl = lane >> 2, cb = (lane & 3) * 4;                                   \
        *(unsigned*)(rowp + (((0*16+cl)^sw)*16 + cb)) = (unsigned)f2bf(a0.x) | ((unsigned)f2bf(a0.y) << 16); \
        *(unsigned*)(rowp + (((1*16+cl)^sw)*16 + cb)) = (unsigned)f2bf(a1.x) | ((unsigned)f2bf(a1.y) << 16); \
        *(unsigned*)(rowp + (((2*16+cl)^sw)*16 + cb)) = (unsigned)f2bf(a2.x) | ((unsigned)f2bf(a2.y) << 16); \
        *(unsigned*)(rowp + (((3*16+cl)^sw)*16 + cb)) = (unsigned)f2bf(a3.x) | ((unsigned)f2bf(a3.y) << 16); \
        *(unsigned*)(rowp + (((4*16+cl)^sw)*16 + cb)) = (unsigned)f2bf(a4.x) | ((unsigned)f2bf(a4.y) << 16); \
        *(unsigned*)(rowp + (((5*16+cl)^sw)*16 + cb)) = (unsigned)f2bf(a5.x) | ((unsigned)f2bf(a5.y) << 16); \
        *(unsigned*)(rowp + (((6*16+cl)^sw)*16 + cb)) = (unsigned)f2bf(a6.x) | ((unsigned)f2bf(a6.y) << 16); \
        unsigned hself = *(const unsigned*)(hb + (size_t)node * DD + lane * 2);    \
        *(unsigned*)(rowp + (((7*16+cl)^sw)*16 + cb)) = hself;                     \
    }

__global__ __launch_bounds__(512) void fused_v3(
        const unsigned short* __restrict__ hb,       // bf16 h  [N][128]
        const int2* __restrict__ segd,
        const int2* __restrict__ edges,              // has >=2 slop entries past EE
        const unsigned short* __restrict__ Wt,       // [128 j][1024 k]
        const float* __restrict__ bias,
        const float* __restrict__ hprev,             // fp32 h  [N][128]
        float* __restrict__ hout,
        unsigned short* __restrict__ hb_next,
        int write_next) {
    __shared__ unsigned short sA[16 * KK];           // 32 KB
    int tid = threadIdx.x;
    int wv = tid >> 6, lane = tid & 63;
    int bm0 = blockIdx.x * 16;

    GATHER_NODE(0)
    GATHER_NODE(1)

    // prefetch epilogue operands (overlap barrier)
    int lm = lane & 15, lg = lane >> 4;
    int j = wv * 16 + lm;
    float bs = bias[j];
    float hp[4];
    #pragma unroll
    for (int v = 0; v < 4; ++v)
        hp[v] = hprev[(size_t)(bm0 + lg * 4 + v) * DD + j];

    __syncthreads();

    // ---- MFMA: wave wv -> cols [16wv, 16wv+16), 16 rows, K=1024 ----
    f32x4 C = {};
    int swm = lm & 7;
    for (int t = 0; t < 32; ++t) {
        short8 af = *(const short8*)((const char*)sA + lm * 2048 + (((t * 4 + lg) ^ swm) * 16));
        short8 bf = *(const short8*)(Wt + (size_t)j * KK + t * 32 + lg * 8);
        C = __builtin_amdgcn_mfma_f32_16x16x32_bf16(af, bf, C, 0, 0, 0);
    }
    #pragma unroll
    for (int v = 0; v < 4; ++v) {
        int gm = bm0 + lg * 4 + v;                   // 3125*16 = 50000 exact
        float val = fmaxf(C[v] + bs, 0.f) + hp[v];
        hout[(size_t)gm * DD + j] = val;
        if (write_next) hb_next[(size_t)gm * DD + j] = f2bf(val);
    }
}

__global__ void zero_gf(float* gf) {
    int t = blockIdx.x * 256 + threadIdx.x;
    if (t < GG * DD) gf[t] = 0.f;
}

// Parallel readout: block = 128 nodes, 8 row-streams x 32 lanes (f32x4 cols).
__global__ __launch_bounds__(256) void readout(const float* __restrict__ h,
                                               const int* __restrict__ n2g,
                                               float* __restrict__ gf) {
    int c0 = blockIdx.x * 128;
    int rg = threadIdx.x >> 5, d4 = threadIdx.x & 31;
    f32x4 acc = {0.f, 0.f, 0.f, 0.f};
    int cur = -1;
    #pragma unroll 4
    for (int it = 0; it < 16; ++it) {
        int row = c0 + it * 8 + rg;
        if (row >= NN) break;
        int g = n2g[row];
        if (g != cur) {
            if (cur >= 0) {
                atomicAdd(&gf[cur * DD + d4 * 4 + 0], acc.x);
                atomicAdd(&gf[cur * DD + d4 * 4 + 1], acc.y);
                atomicAdd(&gf[cur * DD + d4 * 4 + 2], acc.z);
                atomicAdd(&gf[cur * DD + d4 * 4 + 3], acc.w);
            }
            cur = g;
            acc = (f32x4){0.f, 0.f, 0.f, 0.f};
        }
        acc += ((const f32x4*)h)[(size_t)row * 32 + d4];
    }
    if (cur >= 0) {
        atomicAdd(&gf[cur * DD + d4 * 4 + 0], acc.x);
        atomicAdd(&gf[cur * DD + d4 * 4 + 1], acc.y);
        atomicAdd(&gf[cur * DD + d4 * 4 + 2], acc.z);
        atomicAdd(&gf[cur * DD + d4 * 4 + 3], acc.w);
    }
}

extern "C" void kernel_launch(void* const* d_in, const int* in_sizes, int n_in,
                              void* d_out, int out_size, void* d_ws, size_t ws_size,
                              hipStream_t stream) {
    const float* x      = (const float*)d_in[0];
    const int* node_in  = (const int*)d_in[1];
    const int* node_out = (const int*)d_in[2];
    const int* relation = (const int*)d_in[3];
    const float* ew     = (const float*)d_in[4];
    const int* n2g      = (const int*)d_in[5];
    const float* sl_w[3]  = {(const float*)d_in[8],  (const float*)d_in[12], (const float*)d_in[16]};
    const float* sl_b[3]  = {(const float*)d_in[9],  (const float*)d_in[13], (const float*)d_in[17]};
    const float* lin_w[3] = {(const float*)d_in[10], (const float*)d_in[14], (const float*)d_in[18]};
    const float* lin_b[3] = {(const float*)d_in[11], (const float*)d_in[15], (const float*)d_in[19]};

    float* out = (float*)d_out;
    float* gf = out;                       // [G,D]
    float* nf = out + GG * DD;             // [N,D] node_feature (doubles as h buffer)

    char* ws = (char*)d_ws;
    size_t off = 0;
    unsigned short* hb0 = (unsigned short*)(ws + off); off += (size_t)NN * DD * 2;    // 12.8 MB
    unsigned short* hb1 = (unsigned short*)(ws + off); off += (size_t)NN * DD * 2;    // 12.8 MB
    float* hA   = (float*)(ws + off);            off += (size_t)NN * DD * 4;          // 25.6 MB
    unsigned short* Wt = (unsigned short*)(ws + off); off += (size_t)3 * KK * DD * 2;
    float* bias = (float*)(ws + off);            off += 3 * DD * 4;
    int* counts = (int*)(ws + off);              off += (size_t)NSEG * 4;
    int* cursor = (int*)(ws + off);              off += (size_t)NSEG * 4;
    int* start  = (int*)(ws + off);              off += (size_t)NSEG * 4;
    int2* segd  = (int2*)(ws + off);             off += (size_t)NSEG * 8;
    int* bsum   = (int*)(ws + off);              off += 512 * 4;
    int2* edges = (int2*)(ws + off);             off += (size_t)(EE + 8) * 8;         // +slop

    for (int l = 0; l < 3; ++l)
        prep_w<<<512, 256, 0, stream>>>(lin_w[l], sl_w[l], lin_b[l], sl_b[l],
                                        Wt + (size_t)l * KK * DD, bias + l * DD);

    // CSR build (edge topology is layer-invariant)
    zero_ints<<<(2 * NSEG + 255) / 256, 256, 0, stream>>>(counts, 2 * NSEG);
    hist<<<(EE + 255) / 256, 256, 0, stream>>>(node_out, relation, counts);
    scan1<<<NB1, 256, 0, stream>>>(counts, start, bsum);
    scan2<<<1, 512, 0, stream>>>(bsum);
    scan3<<<(NSEG + 255) / 256, 256, 0, stream>>>(start, bsum, counts, segd);
    fill<<<(EE + 255) / 256, 256, 0, stream>>>(node_in, node_out, relation, ew,
                                               segd, cursor, edges);
    init_hb<<<(NN * 32) / 256, 256, 0, stream>>>(x, hb0);   // 6250 blocks exact

    const float* hcur = x;
    float* houts[3] = { nf, hA, nf };
    unsigned short* hbs[2] = { hb0, hb1 };
    for (int l = 0; l < 3; ++l) {
        fused_v3<<<NN / 16, 512, 0, stream>>>(
            hbs[l & 1], segd, edges, Wt + (size_t)l * KK * DD, bias + l * DD,
            hcur, houts[l], hbs[(l + 1) & 1], l < 2 ? 1 : 0);
        hcur = houts[l];
    }
    zero_gf<<<(GG * DD + 255) / 256, 256, 0, stream>>>(gf);
    readout<<<(NN + 127) / 128, 256, 0, stream>>>(nf, n2g, gf);
}

// Round 11
// 433.300 us; speedup vs baseline: 1.3434x; 1.2663x over previous
//
#include <hip/hip_runtime.h>
#include <hip/hip_bf16.h>

#define NN 50000
#define EE 600000
#define DD 128
#define RR 7
#define SS 8            // R + self-loop slot
#define GG 32
#define NSEG (NN * RR)  // 350000 CSR segments
#define NB1 ((NSEG + 1023) / 1024)   // 342 scan blocks

typedef float f32x4 __attribute__((ext_vector_type(4)));
typedef float f32x2 __attribute__((ext_vector_type(2)));
typedef short short8 __attribute__((ext_vector_type(8)));
typedef unsigned short u16x8 __attribute__((ext_vector_type(8)));

static __device__ __forceinline__ unsigned short f2bf(float f) {
    union { float f; unsigned u; } v; v.f = f;
    unsigned r = v.u + 0x7fff + ((v.u >> 16) & 1);
    return (unsigned short)(r >> 16);
}
static __device__ __forceinline__ float bf2f(unsigned short u) {
    union { unsigned u; float f; } v; v.u = ((unsigned)u) << 16;
    return v.f;
}

// ---- weights prep: Wt2[j=(slot,dout)][k=din] bf16; bias = lin_b + sl_b ----
__global__ void prep_w2(const float* __restrict__ lin_w, const float* __restrict__ sl_w,
                        const float* __restrict__ lin_b, const float* __restrict__ sl_b,
                        unsigned short* __restrict__ Wt2, float* __restrict__ bias) {
    int idx = blockIdx.x * 256 + threadIdx.x;   // 131072
    if (idx < DD) bias[idx] = lin_b[idx] + sl_b[idx];
    if (idx >= 1024 * DD) return;
    int j = idx >> 7;                  // output col: slot*128 + dout
    int k = idx & 127;                 // din
    int slot = j >> 7, dout = j & 127;
    float w = (slot < 7) ? lin_w[(slot * DD + k) * DD + dout] : sl_w[k * DD + dout];
    Wt2[(size_t)j * DD + k] = f2bf(w);
}

// ---------------- CSR build ----------------
__global__ void zero_ints(int* __restrict__ p, int n) {
    int i = blockIdx.x * 256 + threadIdx.x;
    if (i < n) p[i] = 0;
}

__global__ void hist(const int* __restrict__ node_out, const int* __restrict__ rel,
                     int* __restrict__ counts) {
    int e = blockIdx.x * 256 + threadIdx.x;
    if (e >= EE) return;
    atomicAdd(&counts[node_out[e] * RR + rel[e]], 1);
}

__global__ __launch_bounds__(256) void scan1(const int* __restrict__ counts,
                                             int* __restrict__ start, int* __restrict__ bsum) {
    __shared__ int s[256];
    int tid = threadIdx.x;
    int base = blockIdx.x * 1024 + tid * 4;
    int v[4], sum = 0;
    #pragma unroll
    for (int j = 0; j < 4; ++j) {
        v[j] = (base + j < NSEG) ? counts[base + j] : 0;
        sum += v[j];
    }
    s[tid] = sum; __syncthreads();
    for (int off = 1; off < 256; off <<= 1) {
        int t = (tid >= off) ? s[tid - off] : 0;
        __syncthreads();
        s[tid] += t;
        __syncthreads();
    }
    int run = s[tid] - sum;
    if (tid == 255) bsum[blockIdx.x] = s[255];
    #pragma unroll
    for (int j = 0; j < 4; ++j) {
        if (base + j < NSEG) { start[base + j] = run; run += v[j]; }
    }
}

__global__ __launch_bounds__(512) void scan2(int* __restrict__ bsum) {
    __shared__ int s[512];
    int tid = threadIdx.x;
    int v = (tid < NB1) ? bsum[tid] : 0;
    s[tid] = v; __syncthreads();
    for (int off = 1; off < 512; off <<= 1) {
        int t = (tid >= off) ? s[tid - off] : 0;
        __syncthreads();
        s[tid] += t;
        __syncthreads();
    }
    if (tid < NB1) bsum[tid] = s[tid] - v;
}

__global__ void scan3(const int* __restrict__ start, const int* __restrict__ bsum,
                      const int* __restrict__ counts, int2* __restrict__ segd) {
    int i = blockIdx.x * 256 + threadIdx.x;
    if (i < NSEG) segd[i] = make_int2(start[i] + bsum[i >> 10], counts[i]);
}

// record: x = (rel << 16) | node_in, y = weight bits
__global__ void fill(const int* __restrict__ node_in, const int* __restrict__ node_out,
                     const int* __restrict__ rel, const float* __restrict__ ew,
                     const int2* __restrict__ segd, int* __restrict__ cursor,
                     int2* __restrict__ edges) {
    int e = blockIdx.x * 256 + threadIdx.x;
    if (e >= EE) return;
    int seg = node_out[e] * RR + rel[e];
    int pos = segd[seg].x + atomicAdd(&cursor[seg], 1);
    edges[pos] = make_int2((rel[e] << 16) | node_in[e], __float_as_int(ew[e]));
}

// layer-0 bf16 shadow of x.  EXACTLY NN*32 threads (6250 blocks).
__global__ void init_hb(const float* __restrict__ x, unsigned short* __restrict__ hb) {
    int t = blockIdx.x * 256 + threadIdx.x;     // [0, NN*32)
    if (t >= NN * 32) return;
    f32x4 v = ((const f32x4*)x)[t];
    unsigned long long pack = (unsigned long long)f2bf(v.x)
                            | ((unsigned long long)f2bf(v.y) << 16)
                            | ((unsigned long long)f2bf(v.z) << 32)
                            | ((unsigned long long)f2bf(v.w) << 48);
    ((unsigned long long*)hb)[t] = pack;
}

// ---- dense GEMM: P[n][1024] = hb[n][128] @ Wcat; bf16 out ----
// grid = ceil(N/128) * 8 col-blocks; block = 256 thr = 4 waves (2x2, 64x64 each)
__global__ __launch_bounds__(256) void gemm_p(
        const unsigned short* __restrict__ hb,   // [N][128] bf16
        const unsigned short* __restrict__ Wt2,  // [1024][128] bf16
        unsigned short* __restrict__ P) {        // [N][1024] bf16
    __shared__ unsigned short sA[128 * 128];     // 32 KB, u16x8 chunks, XOR-swizzled
    int tid = threadIdx.x;
    int bm0 = (blockIdx.x >> 3) * 128;
    int bj0 = (blockIdx.x & 7) * 128;
    #pragma unroll
    for (int it = 0; it < 8; ++it) {
        int cid = it * 256 + tid;                // [0,2048) chunks of 8 bf16
        int row = cid >> 4, c = cid & 15;
        int gr = bm0 + row;
        u16x8 t8 = {};
        if (gr < NN) t8 = *(const u16x8*)(hb + (size_t)gr * DD + c * 8);
        ((u16x8*)sA)[row * 16 + (c ^ (row & 7))] = t8;
    }
    __syncthreads();
    int wid = tid >> 6, lane = tid & 63;
    int wr = wid >> 1, wc = wid & 1;
    int lm = lane & 15, lg = lane >> 4;
    f32x4 acc[4][4] = {};
    #pragma unroll
    for (int ks = 0; ks < 4; ++ks) {
        short8 af[4], bfr[4];
        #pragma unroll
        for (int mi = 0; mi < 4; ++mi) {
            int row = wr * 64 + mi * 16 + lm;
            af[mi] = ((const short8*)sA)[row * 16 + ((ks * 4 + lg) ^ (row & 7))];
        }
        #pragma unroll
        for (int ni = 0; ni < 4; ++ni)
            bfr[ni] = *(const short8*)(Wt2 + (size_t)(bj0 + wc * 64 + ni * 16 + lm) * DD + ks * 32 + lg * 8);
        #pragma unroll
        for (int mi = 0; mi < 4; ++mi)
            #pragma unroll
            for (int ni = 0; ni < 4; ++ni)
                acc[mi][ni] = __builtin_amdgcn_mfma_f32_16x16x32_bf16(af[mi], bfr[ni], acc[mi][ni], 0, 0, 0);
    }
    #pragma unroll
    for (int mi = 0; mi < 4; ++mi) {
        #pragma unroll
        for (int v = 0; v < 4; ++v) {
            int gm = bm0 + wr * 64 + mi * 16 + lg * 4 + v;
            if (gm >= NN) continue;
            #pragma unroll
            for (int ni = 0; ni < 4; ++ni) {
                int j = bj0 + wc * 64 + ni * 16 + lm;
                P[(size_t)gm * 1024 + j] = f2bf(acc[mi][ni][v]);
            }
        }
    }
}

// ---- gather in P-space: wave per node, 3-deep pipelined, single f32x2 acc ----
// out[n] = relu(sum_e w_e * P[src_e*8+rel_e] + P[n*8+7] + bias) + hprev[n]
__global__ __launch_bounds__(256) void gather_p(
        const unsigned short* __restrict__ P,    // [N][8][128] bf16
        const int2* __restrict__ segd,
        const int2* __restrict__ edges,          // +8 zeroed slop records
        const float* __restrict__ bias,
        const float* __restrict__ hprev,         // fp32 [N][128]
        float* __restrict__ hout,
        unsigned short* __restrict__ hb_next,
        int write_next) {
    int tid = threadIdx.x;
    int wv = tid >> 6, lane = tid & 63;
    int node = blockIdx.x * 4 + wv;              // 12500*4 = 50000 exact
    int st = segd[node * RR].x;
    int2 s6 = segd[node * RR + 6];
    int end = s6.x + s6.y;

    float ax = 0.f, ay = 0.f;
    int2 r0 = edges[st];
    int2 r1 = edges[st + 1];
    int2 r2 = edges[st + 2];
    unsigned hv0 = *(const unsigned*)(P + (size_t)(((r0.x & 0xFFFF) << 3) | (r0.x >> 16)) * DD + lane * 2);
    unsigned hv1 = *(const unsigned*)(P + (size_t)(((r1.x & 0xFFFF) << 3) | (r1.x >> 16)) * DD + lane * 2);
    for (int i = st; i < end; ++i) {
        int2 r3 = edges[i + 3];
        unsigned hv2 = *(const unsigned*)(P + (size_t)(((r2.x & 0xFFFF) << 3) | (r2.x >> 16)) * DD + lane * 2);
        float w = __int_as_float(r0.y);
        ax += bf2f((unsigned short)(hv0 & 0xFFFF)) * w;
        ay += bf2f((unsigned short)(hv0 >> 16)) * w;
        r0 = r1; r1 = r2; r2 = r3;
        hv0 = hv1; hv1 = hv2;
    }
    unsigned hs = *(const unsigned*)(P + ((size_t)node * 8 + 7) * DD + lane * 2);
    float bx = bias[lane * 2], by = bias[lane * 2 + 1];
    f32x2 hp = ((const f32x2*)hprev)[(size_t)node * 64 + lane];
    float vx = fmaxf(ax + bf2f((unsigned short)(hs & 0xFFFF)) + bx, 0.f) + hp.x;
    float vy = fmaxf(ay + bf2f((unsigned short)(hs >> 16)) + by, 0.f) + hp.y;
    ((f32x2*)hout)[(size_t)node * 64 + lane] = (f32x2){vx, vy};
    if (write_next)
        ((unsigned*)hb_next)[(size_t)node * 64 + lane] =
            (unsigned)f2bf(vx) | ((unsigned)f2bf(vy) << 16);
}

__global__ void zero_gf(float* gf) {
    int t = blockIdx.x * 256 + threadIdx.x;
    if (t < GG * DD) gf[t] = 0.f;
}

// Parallel readout: block = 128 nodes, 8 row-streams x 32 lanes (f32x4 cols).
__global__ __launch_bounds__(256) void readout(const float* __restrict__ h,
                                               const int* __restrict__ n2g,
                                               float* __restrict__ gf) {
    int c0 = blockIdx.x * 128;
    int rg = threadIdx.x >> 5, d4 = threadIdx.x & 31;
    f32x4 acc = {0.f, 0.f, 0.f, 0.f};
    int cur = -1;
    #pragma unroll 4
    for (int it = 0; it < 16; ++it) {
        int row = c0 + it * 8 + rg;
        if (row >= NN) break;
        int g = n2g[row];
        if (g != cur) {
            if (cur >= 0) {
                atomicAdd(&gf[cur * DD + d4 * 4 + 0], acc.x);
                atomicAdd(&gf[cur * DD + d4 * 4 + 1], acc.y);
                atomicAdd(&gf[cur * DD + d4 * 4 + 2], acc.z);
                atomicAdd(&gf[cur * DD + d4 * 4 + 3], acc.w);
            }
            cur = g;
            acc = (f32x4){0.f, 0.f, 0.f, 0.f};
        }
        acc += ((const f32x4*)h)[(size_t)row * 32 + d4];
    }
    if (cur >= 0) {
        atomicAdd(&gf[cur * DD + d4 * 4 + 0], acc.x);
        atomicAdd(&gf[cur * DD + d4 * 4 + 1], acc.y);
        atomicAdd(&gf[cur * DD + d4 * 4 + 2], acc.z);
        atomicAdd(&gf[cur * DD + d4 * 4 + 3], acc.w);
    }
}

extern "C" void kernel_launch(void* const* d_in, const int* in_sizes, int n_in,
                              void* d_out, int out_size, void* d_ws, size_t ws_size,
                              hipStream_t stream) {
    const float* x      = (const float*)d_in[0];
    const int* node_in  = (const int*)d_in[1];
    const int* node_out = (const int*)d_in[2];
    const int* relation = (const int*)d_in[3];
    const float* ew     = (const float*)d_in[4];
    const int* n2g      = (const int*)d_in[5];
    const float* sl_w[3]  = {(const float*)d_in[8],  (const float*)d_in[12], (const float*)d_in[16]};
    const float* sl_b[3]  = {(const float*)d_in[9],  (const float*)d_in[13], (const float*)d_in[17]};
    const float* lin_w[3] = {(const float*)d_in[10], (const float*)d_in[14], (const float*)d_in[18]};
    const float* lin_b[3] = {(const float*)d_in[11], (const float*)d_in[15], (const float*)d_in[19]};

    float* out = (float*)d_out;
    float* gf = out;                       // [G,D]
    float* nf = out + GG * DD;             // [N,D]

    char* ws = (char*)d_ws;
    size_t off = 0;
    unsigned short* P  = (unsigned short*)(ws + off); off += (size_t)NN * 1024 * 2;   // 102.4 MB
    unsigned short* hb0 = (unsigned short*)(ws + off); off += (size_t)NN * DD * 2;    // 12.8 MB
    unsigned short* hb1 = (unsigned short*)(ws + off); off += (size_t)NN * DD * 2;    // 12.8 MB
    float* hA   = (float*)(ws + off);            off += (size_t)NN * DD * 4;          // 25.6 MB
    unsigned short* Wt2 = (unsigned short*)(ws + off); off += (size_t)3 * 1024 * DD * 2;
    float* bias = (float*)(ws + off);            off += 3 * DD * 4;
    int* counts = (int*)(ws + off);              off += (size_t)NSEG * 4;
    int* cursor = (int*)(ws + off);              off += (size_t)NSEG * 4;
    int* start  = (int*)(ws + off);              off += (size_t)NSEG * 4;
    int2* segd  = (int2*)(ws + off);             off += (size_t)NSEG * 8;
    int* bsum   = (int*)(ws + off);              off += 512 * 4;
    int2* edges = (int2*)(ws + off);             off += (size_t)(EE + 8) * 8;         // +slop

    for (int l = 0; l < 3; ++l)
        prep_w2<<<512, 256, 0, stream>>>(lin_w[l], sl_w[l], lin_b[l], sl_b[l],
                                         Wt2 + (size_t)l * 1024 * DD, bias + l * DD);

    // CSR build (layer-invariant)
    zero_ints<<<(2 * NSEG + 255) / 256, 256, 0, stream>>>(counts, 2 * NSEG);
    zero_ints<<<1, 64, 0, stream>>>((int*)(edges + EE), 16);   // zero slop records
    hist<<<(EE + 255) / 256, 256, 0, stream>>>(node_out, relation, counts);
    scan1<<<NB1, 256, 0, stream>>>(counts, start, bsum);
    scan2<<<1, 512, 0, stream>>>(bsum);
    scan3<<<(NSEG + 255) / 256, 256, 0, stream>>>(start, bsum, counts, segd);
    fill<<<(EE + 255) / 256, 256, 0, stream>>>(node_in, node_out, relation, ew,
                                               segd, cursor, edges);
    init_hb<<<(NN * 32) / 256, 256, 0, stream>>>(x, hb0);      // 6250 blocks exact

    const float* hcur = x;
    float* houts[3] = { nf, hA, nf };
    unsigned short* hbs[2] = { hb0, hb1 };
    for (int l = 0; l < 3; ++l) {
        gemm_p<<<((NN + 127) / 128) * 8, 256, 0, stream>>>(
            hbs[l & 1], Wt2 + (size_t)l * 1024 * DD, P);
        gather_p<<<NN / 4, 256, 0, stream>>>(
            P, segd, edges, bias + l * DD, hcur, houts[l],
            hbs[(l + 1) & 1], l < 2 ? 1 : 0);
        hcur = houts[l];
    }
    zero_gf<<<(GG * DD + 255) / 256, 256, 0, stream>>>(gf);
    readout<<<(NN + 127) / 128, 256, 0, stream>>>(nf, n2g, gf);
}

// Round 12
// 402.024 us; speedup vs baseline: 1.4480x; 1.0778x over previous
//
#include <hip/hip_runtime.h>
#include <hip/hip_bf16.h>

#define NN 50000
#define EE 600000
#define DD 128
#define RR 7
#define SS 8            // R + self-loop slot
#define GG 32
#define NSEG (NN * RR)  // 350000 CSR segments
#define NB1 ((NSEG + 1023) / 1024)   // 342 scan blocks

typedef float f32x4 __attribute__((ext_vector_type(4)));
typedef float f32x2 __attribute__((ext_vector_type(2)));
typedef short short8 __attribute__((ext_vector_type(8)));
typedef unsigned short u16x8 __attribute__((ext_vector_type(8)));

static __device__ __forceinline__ unsigned short f2bf(float f) {
    union { float f; unsigned u; } v; v.f = f;
    unsigned r = v.u + 0x7fff + ((v.u >> 16) & 1);
    return (unsigned short)(r >> 16);
}
static __device__ __forceinline__ float bf2f(unsigned short u) {
    union { unsigned u; float f; } v; v.u = ((unsigned)u) << 16;
    return v.f;
}

// ---- weights prep: Wt2[j=(slot,dout)][k=din] bf16; bias = lin_b + sl_b ----
__global__ void prep_w2(const float* __restrict__ lin_w, const float* __restrict__ sl_w,
                        const float* __restrict__ lin_b, const float* __restrict__ sl_b,
                        unsigned short* __restrict__ Wt2, float* __restrict__ bias) {
    int idx = blockIdx.x * 256 + threadIdx.x;   // 131072
    if (idx < DD) bias[idx] = lin_b[idx] + sl_b[idx];
    if (idx >= 1024 * DD) return;
    int j = idx >> 7;                  // output col: slot*128 + dout
    int k = idx & 127;                 // din
    int slot = j >> 7, dout = j & 127;
    float w = (slot < 7) ? lin_w[(slot * DD + k) * DD + dout] : sl_w[k * DD + dout];
    Wt2[(size_t)j * DD + k] = f2bf(w);
}

// ---------------- CSR build ----------------
__global__ void zero_ints(int* __restrict__ p, int n) {
    int i = blockIdx.x * 256 + threadIdx.x;
    if (i < n) p[i] = 0;
}

__global__ void hist(const int* __restrict__ node_out, const int* __restrict__ rel,
                     int* __restrict__ counts) {
    int e = blockIdx.x * 256 + threadIdx.x;
    if (e >= EE) return;
    atomicAdd(&counts[node_out[e] * RR + rel[e]], 1);
}

__global__ __launch_bounds__(256) void scan1(const int* __restrict__ counts,
                                             int* __restrict__ start, int* __restrict__ bsum) {
    __shared__ int s[256];
    int tid = threadIdx.x;
    int base = blockIdx.x * 1024 + tid * 4;
    int v[4], sum = 0;
    #pragma unroll
    for (int j = 0; j < 4; ++j) {
        v[j] = (base + j < NSEG) ? counts[base + j] : 0;
        sum += v[j];
    }
    s[tid] = sum; __syncthreads();
    for (int off = 1; off < 256; off <<= 1) {
        int t = (tid >= off) ? s[tid - off] : 0;
        __syncthreads();
        s[tid] += t;
        __syncthreads();
    }
    int run = s[tid] - sum;
    if (tid == 255) bsum[blockIdx.x] = s[255];
    #pragma unroll
    for (int j = 0; j < 4; ++j) {
        if (base + j < NSEG) { start[base + j] = run; run += v[j]; }
    }
}

__global__ __launch_bounds__(512) void scan2(int* __restrict__ bsum) {
    __shared__ int s[512];
    int tid = threadIdx.x;
    int v = (tid < NB1) ? bsum[tid] : 0;
    s[tid] = v; __syncthreads();
    for (int off = 1; off < 512; off <<= 1) {
        int t = (tid >= off) ? s[tid - off] : 0;
        __syncthreads();
        s[tid] += t;
        __syncthreads();
    }
    if (tid < NB1) bsum[tid] = s[tid] - v;
}

__global__ void scan3(const int* __restrict__ start, const int* __restrict__ bsum,
                      const int* __restrict__ counts, int2* __restrict__ segd) {
    int i = blockIdx.x * 256 + threadIdx.x;
    if (i < NSEG) segd[i] = make_int2(start[i] + bsum[i >> 10], counts[i]);
}

// record: x = (rel << 16) | node_in, y = weight bits
__global__ void fill(const int* __restrict__ node_in, const int* __restrict__ node_out,
                     const int* __restrict__ rel, const float* __restrict__ ew,
                     const int2* __restrict__ segd, int* __restrict__ cursor,
                     int2* __restrict__ edges) {
    int e = blockIdx.x * 256 + threadIdx.x;
    if (e >= EE) return;
    int seg = node_out[e] * RR + rel[e];
    int pos = segd[seg].x + atomicAdd(&cursor[seg], 1);
    edges[pos] = make_int2((rel[e] << 16) | node_in[e], __float_as_int(ew[e]));
}

// layer-0 bf16 shadow of x.  EXACTLY NN*32 threads (6250 blocks).
__global__ void init_hb(const float* __restrict__ x, unsigned short* __restrict__ hb) {
    int t = blockIdx.x * 256 + threadIdx.x;     // [0, NN*32)
    if (t >= NN * 32) return;
    f32x4 v = ((const f32x4*)x)[t];
    unsigned long long pack = (unsigned long long)f2bf(v.x)
                            | ((unsigned long long)f2bf(v.y) << 16)
                            | ((unsigned long long)f2bf(v.z) << 32)
                            | ((unsigned long long)f2bf(v.w) << 48);
    ((unsigned long long*)hb)[t] = pack;
}

// ---- dense GEMM v2: P[n][1024] = hb[n][128] @ Wcat; A in registers, no LDS ----
// grid = ceil(N/128) blocks; 256 thr = 4 waves (2x2 over 128 rows x 64 cols),
// loop 8 col-blocks of 128; A frags (64 VGPR) loaded once, W streamed from L2.
__global__ __launch_bounds__(256) void gemm_p(
        const unsigned short* __restrict__ hb,   // [N][128] bf16
        const unsigned short* __restrict__ Wt2,  // [1024][128] bf16
        unsigned short* __restrict__ P) {        // [N][1024] bf16
    int tid = threadIdx.x;
    int wid = tid >> 6, lane = tid & 63;
    int wr = wid >> 1, wc = wid & 1;
    int lm = lane & 15, lg = lane >> 4;
    int bm0 = blockIdx.x * 128;

    // A fragments: rows wr*64 + mi*16 + lm, k = ks*32 + lg*8  (coalesced 64B/row-group)
    short8 af[4][4];
    #pragma unroll
    for (int mi = 0; mi < 4; ++mi) {
        int gr = bm0 + wr * 64 + mi * 16 + lm;
        #pragma unroll
        for (int ks = 0; ks < 4; ++ks) {
            short8 t = {};
            if (gr < NN) t = *(const short8*)(hb + (size_t)gr * DD + ks * 32 + lg * 8);
            af[mi][ks] = t;
        }
    }
    for (int cb = 0; cb < 8; ++cb) {
        f32x4 acc[4][4] = {};
        #pragma unroll
        for (int ks = 0; ks < 4; ++ks) {
            short8 bfr[4];
            #pragma unroll
            for (int ni = 0; ni < 4; ++ni)
                bfr[ni] = *(const short8*)(Wt2 + (size_t)(cb * 128 + wc * 64 + ni * 16 + lm) * DD
                                           + ks * 32 + lg * 8);
            #pragma unroll
            for (int mi = 0; mi < 4; ++mi)
                #pragma unroll
                for (int ni = 0; ni < 4; ++ni)
                    acc[mi][ni] = __builtin_amdgcn_mfma_f32_16x16x32_bf16(af[mi][ks], bfr[ni], acc[mi][ni], 0, 0, 0);
        }
        #pragma unroll
        for (int mi = 0; mi < 4; ++mi) {
            #pragma unroll
            for (int v = 0; v < 4; ++v) {
                int gm = bm0 + wr * 64 + mi * 16 + lg * 4 + v;
                if (gm >= NN) continue;
                #pragma unroll
                for (int ni = 0; ni < 4; ++ni) {
                    int j = cb * 128 + wc * 64 + ni * 16 + lm;
                    P[(size_t)gm * 1024 + j] = f2bf(acc[mi][ni][v]);
                }
            }
        }
    }
}

// ---- gather in P-space: wave per node, 3-deep pipelined, single f32x2 acc ----
// out[n] = relu(sum_e w_e * P[src_e*8+rel_e] + P[n*8+7] + bias) + hprev[n]
__global__ __launch_bounds__(256) void gather_p(
        const unsigned short* __restrict__ P,    // [N][8][128] bf16
        const int2* __restrict__ segd,
        const int2* __restrict__ edges,          // +8 zeroed slop records
        const float* __restrict__ bias,
        const float* __restrict__ hprev,         // fp32 [N][128]
        float* __restrict__ hout,
        unsigned short* __restrict__ hb_next,
        int write_next) {
    int tid = threadIdx.x;
    int wv = tid >> 6, lane = tid & 63;
    int node = blockIdx.x * 4 + wv;              // 12500*4 = 50000 exact
    int st = segd[node * RR].x;
    int2 s6 = segd[node * RR + 6];
    int end = s6.x + s6.y;

    float ax = 0.f, ay = 0.f;
    int2 r0 = edges[st];
    int2 r1 = edges[st + 1];
    int2 r2 = edges[st + 2];
    unsigned hv0 = *(const unsigned*)(P + (size_t)(((r0.x & 0xFFFF) << 3) | (r0.x >> 16)) * DD + lane * 2);
    unsigned hv1 = *(const unsigned*)(P + (size_t)(((r1.x & 0xFFFF) << 3) | (r1.x >> 16)) * DD + lane * 2);
    for (int i = st; i < end; ++i) {
        int2 r3 = edges[i + 3];
        unsigned hv2 = *(const unsigned*)(P + (size_t)(((r2.x & 0xFFFF) << 3) | (r2.x >> 16)) * DD + lane * 2);
        float w = __int_as_float(r0.y);
        ax += bf2f((unsigned short)(hv0 & 0xFFFF)) * w;
        ay += bf2f((unsigned short)(hv0 >> 16)) * w;
        r0 = r1; r1 = r2; r2 = r3;
        hv0 = hv1; hv1 = hv2;
    }
    unsigned hs = *(const unsigned*)(P + ((size_t)node * 8 + 7) * DD + lane * 2);
    float bx = bias[lane * 2], by = bias[lane * 2 + 1];
    f32x2 hp = ((const f32x2*)hprev)[(size_t)node * 64 + lane];
    float vx = fmaxf(ax + bf2f((unsigned short)(hs & 0xFFFF)) + bx, 0.f) + hp.x;
    float vy = fmaxf(ay + bf2f((unsigned short)(hs >> 16)) + by, 0.f) + hp.y;
    ((f32x2*)hout)[(size_t)node * 64 + lane] = (f32x2){vx, vy};
    if (write_next)
        ((unsigned*)hb_next)[(size_t)node * 64 + lane] =
            (unsigned)f2bf(vx) | ((unsigned)f2bf(vy) << 16);
}

__global__ void zero_gf(float* gf) {
    int t = blockIdx.x * 256 + threadIdx.x;
    if (t < GG * DD) gf[t] = 0.f;
}

// Parallel readout: block = 128 nodes, 8 row-streams x 32 lanes (f32x4 cols).
__global__ __launch_bounds__(256) void readout(const float* __restrict__ h,
                                               const int* __restrict__ n2g,
                                               float* __restrict__ gf) {
    int c0 = blockIdx.x * 128;
    int rg = threadIdx.x >> 5, d4 = threadIdx.x & 31;
    f32x4 acc = {0.f, 0.f, 0.f, 0.f};
    int cur = -1;
    #pragma unroll 4
    for (int it = 0; it < 16; ++it) {
        int row = c0 + it * 8 + rg;
        if (row >= NN) break;
        int g = n2g[row];
        if (g != cur) {
            if (cur >= 0) {
                atomicAdd(&gf[cur * DD + d4 * 4 + 0], acc.x);
                atomicAdd(&gf[cur * DD + d4 * 4 + 1], acc.y);
                atomicAdd(&gf[cur * DD + d4 * 4 + 2], acc.z);
                atomicAdd(&gf[cur * DD + d4 * 4 + 3], acc.w);
            }
            cur = g;
            acc = (f32x4){0.f, 0.f, 0.f, 0.f};
        }
        acc += ((const f32x4*)h)[(size_t)row * 32 + d4];
    }
    if (cur >= 0) {
        atomicAdd(&gf[cur * DD + d4 * 4 + 0], acc.x);
        atomicAdd(&gf[cur * DD + d4 * 4 + 1], acc.y);
        atomicAdd(&gf[cur * DD + d4 * 4 + 2], acc.z);
        atomicAdd(&gf[cur * DD + d4 * 4 + 3], acc.w);
    }
}

extern "C" void kernel_launch(void* const* d_in, const int* in_sizes, int n_in,
                              void* d_out, int out_size, void* d_ws, size_t ws_size,
                              hipStream_t stream) {
    const float* x      = (const float*)d_in[0];
    const int* node_in  = (const int*)d_in[1];
    const int* node_out = (const int*)d_in[2];
    const int* relation = (const int*)d_in[3];
    const float* ew     = (const float*)d_in[4];
    const int* n2g      = (const int*)d_in[5];
    const float* sl_w[3]  = {(const float*)d_in[8],  (const float*)d_in[12], (const float*)d_in[16]};
    const float* sl_b[3]  = {(const float*)d_in[9],  (const float*)d_in[13], (const float*)d_in[17]};
    const float* lin_w[3] = {(const float*)d_in[10], (const float*)d_in[14], (const float*)d_in[18]};
    const float* lin_b[3] = {(const float*)d_in[11], (const float*)d_in[15], (const float*)d_in[19]};

    float* out = (float*)d_out;
    float* gf = out;                       // [G,D]
    float* nf = out + GG * DD;             // [N,D]

    char* ws = (char*)d_ws;
    size_t off = 0;
    unsigned short* P  = (unsigned short*)(ws + off); off += (size_t)NN * 1024 * 2;   // 102.4 MB
    unsigned short* hb0 = (unsigned short*)(ws + off); off += (size_t)NN * DD * 2;    // 12.8 MB
    unsigned short* hb1 = (unsigned short*)(ws + off); off += (size_t)NN * DD * 2;    // 12.8 MB
    float* hA   = (float*)(ws + off);            off += (size_t)NN * DD * 4;          // 25.6 MB
    unsigned short* Wt2 = (unsigned short*)(ws + off); off += (size_t)3 * 1024 * DD * 2;
    float* bias = (float*)(ws + off);            off += 3 * DD * 4;
    int* counts = (int*)(ws + off);              off += (size_t)NSEG * 4;
    int* cursor = (int*)(ws + off);              off += (size_t)NSEG * 4;
    int* start  = (int*)(ws + off);              off += (size_t)NSEG * 4;
    int2* segd  = (int2*)(ws + off);             off += (size_t)NSEG * 8;
    int* bsum   = (int*)(ws + off);              off += 512 * 4;
    int2* edges = (int2*)(ws + off);             off += (size_t)(EE + 8) * 8;         // +slop

    for (int l = 0; l < 3; ++l)
        prep_w2<<<512, 256, 0, stream>>>(lin_w[l], sl_w[l], lin_b[l], sl_b[l],
                                         Wt2 + (size_t)l * 1024 * DD, bias + l * DD);

    // CSR build (layer-invariant)
    zero_ints<<<(2 * NSEG + 255) / 256, 256, 0, stream>>>(counts, 2 * NSEG);
    zero_ints<<<1, 64, 0, stream>>>((int*)(edges + EE), 16);   // zero slop records
    hist<<<(EE + 255) / 256, 256, 0, stream>>>(node_out, relation, counts);
    scan1<<<NB1, 256, 0, stream>>>(counts, start, bsum);
    scan2<<<1, 512, 0, stream>>>(bsum);
    scan3<<<(NSEG + 255) / 256, 256, 0, stream>>>(start, bsum, counts, segd);
    fill<<<(EE + 255) / 256, 256, 0, stream>>>(node_in, node_out, relation, ew,
                                               segd, cursor, edges);
    init_hb<<<(NN * 32) / 256, 256, 0, stream>>>(x, hb0);      // 6250 blocks exact

    const float* hcur = x;
    float* houts[3] = { nf, hA, nf };
    unsigned short* hbs[2] = { hb0, hb1 };
    for (int l = 0; l < 3; ++l) {
        gemm_p<<<(NN + 127) / 128, 256, 0, stream>>>(
            hbs[l & 1], Wt2 + (size_t)l * 1024 * DD, P);
        gather_p<<<NN / 4, 256, 0, stream>>>(
            P, segd, edges, bias + l * DD, hcur, houts[l],
            hbs[(l + 1) & 1], l < 2 ? 1 : 0);
        hcur = houts[l];
    }
    zero_gf<<<(GG * DD + 255) / 256, 256, 0, stream>>>(gf);
    readout<<<(NN + 127) / 128, 256, 0, stream>>>(nf, n2g, gf);
}